// Round 2
// baseline (813.911 us; speedup 1.0000x reference)
//
#include <hip/hip_runtime.h>
#include <hip/hip_bf16.h>

// SpookyNet Performer attention, N=262144, d=128, m=256, f32 in/out.
// out = (Qp·Kp) * V / (Qp·sum_n Kp + 1e-8), Qp/Kp = (exp(U - h - max) + 1e-4)/16
// R1: chunked persistent-ish blocks (512 blocks x 512 rows), omega staged to
// LDS once per block, barrier-free chunk loop with prefetched Q/K raw loads,
// wave-local epilogue. k_kstats uses online max (no in-loop barriers).

typedef _Float16 f16x8 __attribute__((ext_vector_type(8)));
typedef float f32x4 __attribute__((ext_vector_type(4)));

#define D_QK 128
#define M_F  256
#define OMS  136     // omega_t padded row stride in halves (272B) -> conflict-free b128
#define CH   8       // chunks of 64 rows per block
#define ROWS_PER_BLK (CH * 64)

constexpr float D4      = 0.29730177875068026f;   // 128^-0.25
constexpr float H_SCALE = 0.044194173824159216f;  // 1/(2*sqrt(128))

__device__ __forceinline__ unsigned f2key(float f) {
  unsigned b = __float_as_uint(f);
  return (b & 0x80000000u) ? ~b : (b | 0x80000000u);
}
__device__ __forceinline__ float key2f(unsigned k) {
  return (k & 0x80000000u) ? __uint_as_float(k & 0x7fffffffu) : __uint_as_float(~k);
}

__device__ __forceinline__ f32x4 mfma16(f16x8 a, f16x8 b, f32x4 c) {
  return __builtin_amdgcn_mfma_f32_16x16x32_f16(a, b, c, 0, 0, 0);
}

// Issue the 8 float4 loads for this lane's A-fragment source (row ptr already
// offset by q*8).
__device__ __forceinline__ void issue_loads(const float* __restrict__ rowq, float4* buf) {
#pragma unroll
  for (int ks = 0; ks < 4; ++ks) {
    const float4* p = (const float4*)(rowq + ks * 32);
    buf[2 * ks]     = p[0];
    buf[2 * ks + 1] = p[1];
  }
}

// Convert raw float4s -> f16 A-frags + h (wave-reduced over the row).
__device__ __forceinline__ void conv_frag(const float4* buf, f16x8* a, float& h) {
  h = 0.f;
#pragma unroll
  for (int ks = 0; ks < 4; ++ks) {
    float4 x0 = buf[2 * ks], x1 = buf[2 * ks + 1];
    h += x0.x*x0.x + x0.y*x0.y + x0.z*x0.z + x0.w*x0.w
       + x1.x*x1.x + x1.y*x1.y + x1.z*x1.z + x1.w*x1.w;
    f16x8 t;
    t[0] = (_Float16)(x0.x * D4); t[1] = (_Float16)(x0.y * D4);
    t[2] = (_Float16)(x0.z * D4); t[3] = (_Float16)(x0.w * D4);
    t[4] = (_Float16)(x1.x * D4); t[5] = (_Float16)(x1.y * D4);
    t[6] = (_Float16)(x1.z * D4); t[7] = (_Float16)(x1.w * D4);
    a[ks] = t;
  }
  h += __shfl_xor(h, 16, 64);
  h += __shfl_xor(h, 32, 64);
  h *= H_SCALE;
}

// ---------------------------------------------------------------------------
// k_prep: omega (d,m) f32 -> omega_t (m, d) f16 padded; init S=0, Mkey=0.
extern "C" __global__ void k_prep(const float* __restrict__ om, _Float16* __restrict__ omt,
                                  float* __restrict__ S, unsigned* __restrict__ Mkey) {
  int i = blockIdx.x * 256 + threadIdx.x;           // grid = 128 blocks
  if (i < D_QK * M_F) {
    int m = i >> 7, d = i & 127;
    omt[m * OMS + d] = (_Float16)om[d * M_F + m];
  }
  if (blockIdx.x == 0) {
    S[threadIdx.x] = 0.f;
    if (threadIdx.x == 0) *Mkey = 0u;
  }
}

// ---------------------------------------------------------------------------
// k_kstats: each block owns 512 K rows (8 chunks x 64). Online block max +
// column sums of exp(U - h - Lb). No in-loop barriers.
__global__ __launch_bounds__(256, 2) void k_kstats(
    const float* __restrict__ K, const _Float16* __restrict__ omt,
    float* __restrict__ Lout, float* __restrict__ Pout, unsigned* __restrict__ Mkey) {
  __shared__ __align__(16) _Float16 om_lds[M_F * OMS];   // 69632 B
  __shared__ float P_lds[4][256];
  __shared__ float red_lds[4];
  int tid = threadIdx.x;
  int w = tid >> 6, lane = tid & 63, q = lane >> 4, c = lane & 15;

  // stage full omega once
  const float4* osrc = (const float4*)omt;
  float4* odst = (float4*)om_lds;
#pragma unroll
  for (int i = 0; i < 17; ++i) odst[tid + i * 256] = osrc[tid + i * 256];
  __syncthreads();

  const float* kbase = K + ((size_t)blockIdx.x * ROWS_PER_BLK + w * 16 + c) * D_QK + q * 8;

  float4 kraw[8];
  issue_loads(kbase, kraw);

  float Lw = -3.0e38f;
  float ps[16];
#pragma unroll
  for (int t = 0; t < 16; ++t) ps[t] = 0.f;

#pragma unroll 1
  for (int ch = 0; ch < CH; ++ch) {
    f16x8 ak[4];
    float hk;
    conv_frag(kraw, ak, hk);
    if (ch + 1 < CH) issue_loads(kbase + (size_t)(ch + 1) * 64 * D_QK, kraw);

    const f32x4 zero = {0.f, 0.f, 0.f, 0.f};
    f32x4 cc[16];
#pragma unroll
    for (int t = 0; t < 16; ++t) cc[t] = zero;
#pragma unroll
    for (int t = 0; t < 16; ++t)
#pragma unroll
      for (int ks = 0; ks < 4; ++ks) {
        f16x8 b = *(const f16x8*)&om_lds[(t * 16 + c) * OMS + ks * 32 + q * 8];
        cc[t] = mfma16(ak[ks], b, cc[t]);
      }

    // chunk max over this wave's 16 rows x 256 cols
    float mc = cc[0][0];
#pragma unroll
    for (int t = 0; t < 16; ++t)
      mc = fmaxf(mc, fmaxf(fmaxf(cc[t][0], cc[t][1]), fmaxf(cc[t][2], cc[t][3])));
#pragma unroll
    for (int m = 1; m <= 32; m <<= 1) mc = fmaxf(mc, __shfl_xor(mc, m, 64));

    float newL = fmaxf(Lw, mc);
    float f = __expf(Lw - newL);    // 0 on first chunk
    float hr[4];
#pragma unroll
    for (int r = 0; r < 4; ++r) hr[r] = __shfl(hk, q * 4 + r, 64);
#pragma unroll
    for (int t = 0; t < 16; ++t) {
      float s = __expf(cc[t][0] - hr[0] - newL) + __expf(cc[t][1] - hr[1] - newL)
              + __expf(cc[t][2] - hr[2] - newL) + __expf(cc[t][3] - hr[3] - newL);
      ps[t] = ps[t] * f + s;
    }
    Lw = newL;
  }

  // combine the 4 waves
  if (lane == 0) red_lds[w] = Lw;
  __syncthreads();
  float Lb = fmaxf(fmaxf(red_lds[0], red_lds[1]), fmaxf(red_lds[2], red_lds[3]));
  float f = __expf(Lw - Lb);
#pragma unroll
  for (int t = 0; t < 16; ++t) {
    float s = ps[t] * f;
    s += __shfl_xor(s, 16, 64);
    s += __shfl_xor(s, 32, 64);
    if (q == 0) P_lds[w][t * 16 + c] = s;
  }
  __syncthreads();
  Pout[(size_t)blockIdx.x * 256 + tid] =
      P_lds[0][tid] + P_lds[1][tid] + P_lds[2][tid] + P_lds[3][tid];
  if (tid == 0) {
    Lout[blockIdx.x] = Lb;
    atomicMax(Mkey, f2key(Lb));
  }
}

// ---------------------------------------------------------------------------
// k_combine: S[m] = sum_b exp(Lb - M) * P_b[m]; write M as float.
extern "C" __global__ void k_combine(const float* __restrict__ Lout, const float* __restrict__ Pout,
                                     const unsigned* __restrict__ Mkey, float* __restrict__ Mout,
                                     float* __restrict__ S) {
  float M = key2f(*Mkey);
  if (blockIdx.x == 0 && threadIdx.x == 0) *Mout = M;
  int b0 = blockIdx.x * 32;                 // grid = nblk/32
  float acc = 0.f;
  for (int i = 0; i < 32; ++i) {
    int b = b0 + i;
    float f = __expf(Lout[b] - M);
    acc += f * Pout[(size_t)b * 256 + threadIdx.x];
  }
  atomicAdd(&S[threadIdx.x], acc);
}

// ---------------------------------------------------------------------------
// k_main: each block owns 512 rows (8 chunks x 64). Barrier-free chunk loop:
// U_Q & U_K share B-fragments, wave-local scale + V epilogue.
__global__ __launch_bounds__(256, 2) void k_main(
    const float* __restrict__ Q, const float* __restrict__ K, const float* __restrict__ V,
    const _Float16* __restrict__ omt, const float* __restrict__ Sws,
    const float* __restrict__ Mws, float* __restrict__ out, float epsN) {
  __shared__ __align__(16) _Float16 om_lds[M_F * OMS];   // 69632 B
  __shared__ float S_lds[256];
  __shared__ float scale_lds[4][16];
  int tid = threadIdx.x;
  int w = tid >> 6, lane = tid & 63, q = lane >> 4, c = lane & 15;

  S_lds[tid] = (Sws[tid] + epsN) * 0.0625f;   // true sum_n Kp per column
  float Mglob = *Mws;

  const float4* osrc = (const float4*)omt;
  float4* odst = (float4*)om_lds;
#pragma unroll
  for (int i = 0; i < 17; ++i) odst[tid + i * 256] = osrc[tid + i * 256];
  __syncthreads();

  size_t rb0 = ((size_t)blockIdx.x * ROWS_PER_BLK + w * 16 + c) * D_QK + q * 8;
  const float* qbase = Q + rb0;
  const float* kbase = K + rb0;

  float4 qraw[8], kraw[8];
  issue_loads(qbase, qraw);
  issue_loads(kbase, kraw);

#pragma unroll 1
  for (int ch = 0; ch < CH; ++ch) {
    f16x8 aq[4], ak[4];
    float hq, hk;
    conv_frag(qraw, aq, hq);
    conv_frag(kraw, ak, hk);
    if (ch + 1 < CH) {
      issue_loads(qbase + (size_t)(ch + 1) * 64 * D_QK, qraw);
      issue_loads(kbase + (size_t)(ch + 1) * 64 * D_QK, kraw);
    }

    const f32x4 zero = {0.f, 0.f, 0.f, 0.f};
    f32x4 cq[16], ck[16];
#pragma unroll
    for (int t = 0; t < 16; ++t) { cq[t] = zero; ck[t] = zero; }
#pragma unroll
    for (int t = 0; t < 16; ++t)
#pragma unroll
      for (int ks = 0; ks < 4; ++ks) {
        f16x8 b = *(const f16x8*)&om_lds[(t * 16 + c) * OMS + ks * 32 + q * 8];
        cq[t] = mfma16(aq[ks], b, cq[t]);
        ck[t] = mfma16(ak[ks], b, ck[t]);
      }

    float hqr[4], hkr[4];
#pragma unroll
    for (int r = 0; r < 4; ++r) {
      hqr[r] = __shfl(hq, q * 4 + r, 64);
      hkr[r] = __shfl(hk, q * 4 + r, 64);
    }

#pragma unroll
    for (int r = 0; r < 4; ++r) {
      float mx = cq[0][r];
#pragma unroll
      for (int t = 1; t < 16; ++t) mx = fmaxf(mx, cq[t][r]);
#pragma unroll
      for (int m = 1; m <= 8; m <<= 1) mx = fmaxf(mx, __shfl_xor(mx, m, 64));
      float wsum = 0.f, nsum = 0.f;
#pragma unroll
      for (int t = 0; t < 16; ++t) {
        float qp = __expf(cq[t][r] - hqr[r] - mx) + 1e-4f;      // Qp * 16
        float kp = __expf(ck[t][r] - hkr[r] - Mglob) + 1e-4f;   // Kp * 16
        wsum += qp * kp;
        nsum += qp * S_lds[t * 16 + c];
      }
#pragma unroll
      for (int m = 1; m <= 8; m <<= 1) {
        wsum += __shfl_xor(wsum, m, 64);
        nsum += __shfl_xor(nsum, m, 64);
      }
      if (c == 0)
        scale_lds[w][q * 4 + r] = (wsum * (1.f / 256.f)) / (nsum * 0.0625f + 1e-8f);
    }
    // wave-local: writes above are by this wave only; lgkmcnt orders them
    // before the reads below (no __syncthreads needed).
    size_t vbase = ((size_t)blockIdx.x * ROWS_PER_BLK + ch * 64 + w * 16) * D_QK;
    const float4* vsrc = (const float4*)(V + vbase);
    float4* odst4 = (float4*)(out + vbase);
#pragma unroll
    for (int i = 0; i < 8; ++i) {
      int j = i * 64 + lane;                 // 512 float4 = 16 rows x 128 f32
      float s = scale_lds[w][j >> 5];
      float4 v = vsrc[j];
      odst4[j] = make_float4(v.x * s, v.y * s, v.z * s, v.w * s);
    }
  }
}

// ---------------------------------------------------------------------------
extern "C" void kernel_launch(void* const* d_in, const int* in_sizes, int n_in,
                              void* d_out, int out_size, void* d_ws, size_t ws_size,
                              hipStream_t stream) {
  const float* Q  = (const float*)d_in[0];
  const float* K  = (const float*)d_in[1];
  const float* V  = (const float*)d_in[2];
  const float* om = (const float*)d_in[3];
  float* out = (float*)d_out;
  int N = in_sizes[0] / D_QK;               // 262144
  int nblk = N / ROWS_PER_BLK;              // 512

  // ws layout: omt[69632 B] | Lout[nblk*4] | Pout[nblk*256*4] | S[1024] | Mkey | Mout
  char* ws = (char*)d_ws;
  _Float16* omt = (_Float16*)ws;
  size_t off = (size_t)M_F * OMS * 2;
  float* Lout = (float*)(ws + off);   off += (size_t)nblk * 4;
  float* Pout = (float*)(ws + off);   off += (size_t)nblk * 256 * 4;
  float* S    = (float*)(ws + off);   off += 1024;
  unsigned* Mkey = (unsigned*)(ws + off); off += 16;
  float* Mout = (float*)(ws + off);

  hipLaunchKernelGGL(k_prep, dim3((D_QK * M_F + 255) / 256), dim3(256), 0, stream,
                     om, omt, S, Mkey);
  hipLaunchKernelGGL(k_kstats, dim3(nblk), dim3(256), 0, stream, K, omt, Lout, Pout, Mkey);
  hipLaunchKernelGGL(k_combine, dim3(nblk / 32), dim3(256), 0, stream, Lout, Pout, Mkey, Mout, S);
  hipLaunchKernelGGL(k_main, dim3(nblk), dim3(256), 0, stream, Q, K, V, omt, S, Mout, out,
                     (float)N * 1e-4f);
}